// Round 3
// baseline (262.946 us; speedup 1.0000x reference)
//
#include <hip/hip_runtime.h>

// PatchEmbedding2 on MI355X — round 3.
// prep_kernel (1 launch): W->bf16 convert + out:=bias broadcast + token layout.
// gather_kernel: grid(T,B), one block per A row, division-free.
// gemm_kernel: split-K=2 (grid 6x63x2=756 blocks ~3/CU), m97 wave shape
//   (16 MFMA : 8 ds_read), fp32 atomicAdd epilogue onto bias-initialized out.
// Workspace: 64KB + 4.72MB (Wb) + Mpad*3072*2 (~49.5MB) ~= 55 MB.

typedef __attribute__((ext_vector_type(8))) short bf16x8;
typedef __attribute__((ext_vector_type(4))) float f32x4;

#define K_DIM 3072
#define N_DIM 768
#define KSPLIT 2

__device__ __forceinline__ unsigned short f2bf(float f) {
  unsigned int u = __float_as_uint(f);
  u += 0x7fffu + ((u >> 16) & 1u);   // RNE
  return (unsigned short)(u >> 16);
}

__device__ __forceinline__ void gload16(const void* g, void* l) {
  __builtin_amdgcn_global_load_lds(
      (const __attribute__((address_space(1))) void*)g,
      (__attribute__((address_space(3))) void*)l, 16, 0, 0);
}

// ---------------- prep: wconv + bias-init + layout, one launch ----------------
// blocks [0, NB_W): W fp32 -> bf16        (w4 float4-groups)
// blocks [NB_W, NB_W+NB_BIAS): out[m,n] = bias[n]  (out4 float4-groups)
// block NB_W+NB_BIAS: token layout (1024 threads)
__global__ __launch_bounds__(1024)
void prep_kernel(const float* __restrict__ W, unsigned short* __restrict__ Wb, int w4,
                 const float* __restrict__ bias, float* __restrict__ out, int out4,
                 const float* __restrict__ iw, int P,
                 int* __restrict__ tokBase, int* __restrict__ tokMask,
                 int NB_W, int NB_BIAS) {
  int bid = blockIdx.x;
  int tid = threadIdx.x;
  if (bid < NB_W) {
    int idx = bid * 1024 + tid;
    if (idx < w4) {
      float4 f = *(const float4*)(W + (size_t)idx * 4);
      ushort4 o;
      o.x = f2bf(f.x); o.y = f2bf(f.y); o.z = f2bf(f.z); o.w = f2bf(f.w);
      *(ushort4*)(Wb + (size_t)idx * 4) = o;
    }
    return;
  }
  if (bid < NB_W + NB_BIAS) {
    int idx = (bid - NB_W) * 1024 + tid;
    if (idx < out4) {
      int n = (idx % (N_DIM / 4)) * 4;
      *(float4*)(out + (size_t)idx * 4) = *(const float4*)(bias + n);
    }
    return;
  }
  // ---- layout (single block) ----
  __shared__ double s_wsum[16];
  __shared__ double s_avg;
  __shared__ int s_cnt[1024];
  float v = (tid < P) ? iw[tid] : 0.0f;
  double d = (double)v;
#pragma unroll
  for (int off = 32; off > 0; off >>= 1) d += __shfl_down(d, off, 64);
  if ((tid & 63) == 0) s_wsum[tid >> 6] = d;
  __syncthreads();
  if (tid == 0) {
    double s = 0.0;
    for (int i = 0; i < 16; ++i) s += s_wsum[i];
    s_avg = s / (double)P;
  }
  __syncthreads();
  int cnt = 0, sz = 32;
  if (tid < P) {
    double val = 32.0 * pow(s_avg / (double)v, 0.05);
    if (val > 32.0) val = 32.0;
    // nearest of {32,16,8,4}; ties (24,12,6) -> larger (np.argmin first index)
    sz = (val >= 24.0) ? 32 : (val >= 12.0) ? 16 : (val >= 6.0) ? 8 : 4;
    cnt = (sz < 32) ? (32 / sz) : 1;
  }
  s_cnt[tid] = cnt;
  __syncthreads();
  for (int dl = 1; dl < 1024; dl <<= 1) {  // Hillis-Steele inclusive scan
    int add = (tid >= dl) ? s_cnt[tid - dl] : 0;
    __syncthreads();
    s_cnt[tid] += add;
    __syncthreads();
  }
  if (tid < P) {
    int off = s_cnt[tid] - cnt;                 // exclusive offset
    int ini_col = (tid * 32) & 1023;            // (i*ps) % H
    int ini_row = (tid * 32 * 32) >> 10;        // (i*ps*ps) / H
    if (sz == 32) {
      tokBase[off] = ini_row * 1024 + ini_col;
      tokMask[off] = 31;
    } else {
      int ns = 32 / sz;
      for (int j = 0; j < ns; ++j) {
        int r = ini_row + (j * sz) / ns;
        int c = ini_col + ((j * sz) & 31);
        tokBase[off + j] = r * 1024 + c;
        tokMask[off + j] = sz - 1;
      }
    }
  }
}

// ---------------- gather: one block per A row, division-free ----------------
// A[c,f] = patch[c, (f>>log2s)&(s-1), f&(s-1)]  (flat-index periodicity; see r1 note)
__global__ __launch_bounds__(256)
void gather_kernel(const float* __restrict__ x,
                   const int* __restrict__ tokBase,
                   const int* __restrict__ tokMask,
                   unsigned short* __restrict__ Ab) {
  int t = blockIdx.x;            // token
  int b = blockIdx.y;            // batch
  int T = gridDim.x;
  int m = b * T + t;
  int base = tokBase[t];         // blockIdx-uniform -> scalar loads
  int mask = tokMask[t];
  int sh = __popc(mask);
  const float* xb = x + (size_t)b * 3145728 + (size_t)base;
  unsigned short* arow = Ab + (size_t)m * K_DIM;
#pragma unroll
  for (int it = 0; it < 3; ++it) {
    int g = it * 256 + threadIdx.x;   // float4-group 0..767
    int p = g * 4;
    int c = p >> 10;
    int f = p & 1023;
    int h = (f >> sh) & mask;
    int w = f & mask;
    float4 fv = *(const float4*)(xb + (size_t)c * 1048576 + h * 1024 + w);
    ushort4 o;
    o.x = f2bf(fv.x); o.y = f2bf(fv.y); o.z = f2bf(fv.z); o.w = f2bf(fv.w);
    *(ushort4*)(arow + p) = o;
  }
}

// ---------------- gemm: split-K=2, atomicAdd epilogue ----------------
__global__ __launch_bounds__(256, 4)
void gemm_kernel(const unsigned short* __restrict__ A, const unsigned short* __restrict__ Wb,
                 float* __restrict__ out, int Mtot) {
  __shared__ unsigned short Alds[128 * 32];  // 8 KB, NO padding (global_load_lds)
  __shared__ unsigned short Blds[128 * 32];  // 8 KB
  int tid = threadIdx.x;
  int lane = tid & 63;
  int wave = tid >> 6;
  int wr = wave >> 1, wc = wave & 1;
  int mBase = blockIdx.y * 128;
  int nBase = blockIdx.x * 128;
  int kBase = blockIdx.z * (K_DIM / KSPLIT);

  f32x4 acc[4][4] = {};

  int sr = lane >> 2;
  int sc = lane & 3;
  const unsigned short* Ag0 = A + (size_t)(mBase + wave * 32 + sr) * K_DIM + sc * 8 + kBase;
  const unsigned short* Ag1 = Ag0 + (size_t)16 * K_DIM;
  const unsigned short* Bg0 = Wb + (size_t)(nBase + wave * 32 + sr) * K_DIM + sc * 8 + kBase;
  const unsigned short* Bg1 = Bg0 + (size_t)16 * K_DIM;
  unsigned short* Al0 = Alds + wave * 1024 + lane * 8;
  unsigned short* Al1 = Al0 + 512;
  unsigned short* Bl0 = Blds + wave * 1024 + lane * 8;
  unsigned short* Bl1 = Bl0 + 512;

  int rr = lane & 15, q = lane >> 4;

  for (int k0 = 0; k0 < K_DIM / KSPLIT; k0 += 32) {
    gload16(Ag0 + k0, Al0);
    gload16(Ag1 + k0, Al1);
    gload16(Bg0 + k0, Bl0);
    gload16(Bg1 + k0, Bl1);
    __syncthreads();

    bf16x8 aF[4], bF[4];
#pragma unroll
    for (int i = 0; i < 4; ++i)
      aF[i] = *(const bf16x8*)&Alds[(wr * 64 + i * 16 + rr) * 32 + q * 8];
#pragma unroll
    for (int j = 0; j < 4; ++j)
      bF[j] = *(const bf16x8*)&Blds[(wc * 64 + j * 16 + rr) * 32 + q * 8];
#pragma unroll
    for (int i = 0; i < 4; ++i)
#pragma unroll
      for (int j = 0; j < 4; ++j)
        acc[i][j] = __builtin_amdgcn_mfma_f32_16x16x32_bf16(aF[i], bF[j], acc[i][j], 0, 0, 0);
    __syncthreads();
  }

  // epilogue: C/D layout col=lane&15, row=(lane>>4)*4+reg; bias already in out
#pragma unroll
  for (int j = 0; j < 4; ++j) {
    int n = nBase + wc * 64 + j * 16 + rr;
#pragma unroll
    for (int i = 0; i < 4; ++i) {
      int mrow = mBase + wr * 64 + i * 16 + q * 4;
#pragma unroll
      for (int r2 = 0; r2 < 4; ++r2) {
        int m = mrow + r2;
        if (m < Mtot) atomicAdd(&out[(size_t)m * N_DIM + n], acc[i][j][r2]);
      }
    }
  }
}

extern "C" void kernel_launch(void* const* d_in, const int* in_sizes, int n_in,
                              void* d_out, int out_size, void* d_ws, size_t ws_size,
                              hipStream_t stream) {
  const float* x  = (const float*)d_in[0];
  const float* iw = (const float*)d_in[1];
  const float* W  = (const float*)d_in[2];
  const float* b  = (const float*)d_in[3];
  int P = in_sizes[1];                        // 992
  int B = in_sizes[0] / (3 * 1024 * 1024);    // 8
  int E = in_sizes[3];                        // 768
  int T = out_size / (B * E);                 // 995
  int Mtot = B * T;                           // 7960
  int Mpad = (Mtot + 127) & ~127;             // 8064

  char* ws = (char*)d_ws;
  int* tokBase = (int*)ws;                              // 32 KB
  int* tokMask = (int*)(ws + 32768);                    // 32 KB
  unsigned short* Wb = (unsigned short*)(ws + 65536);   // 4.72 MB
  unsigned short* Ab = (unsigned short*)(ws + 65536 + (size_t)E * K_DIM * 2);

  int w4 = E * K_DIM / 4;                     // 589824
  int out4 = out_size / 4;                    // 1528320
  int NB_W = (w4 + 1023) / 1024;              // 576
  int NB_BIAS = (out4 + 1023) / 1024;         // 1493
  prep_kernel<<<NB_W + NB_BIAS + 1, 1024, 0, stream>>>(
      W, Wb, w4, b, (float*)d_out, out4, iw, P, tokBase, tokMask, NB_W, NB_BIAS);

  dim3 gGrid(T, B);
  gather_kernel<<<gGrid, 256, 0, stream>>>(x, tokBase, tokMask, Ab);

  dim3 grid(N_DIM / 128, Mpad / 128, KSPLIT);
  gemm_kernel<<<grid, 256, 0, stream>>>(Ab, Wb, (float*)d_out, Mtot);
}

// Round 4
// 262.238 us; speedup vs baseline: 1.0027x; 1.0027x over previous
//
#include <hip/hip_runtime.h>

// PatchEmbedding2 on MI355X — round 4.
// prep_kernel: W->bf16 + token layout (1 launch).
// gather_kernel: one block per A row (token), division-free.
// gemm_kernel: 128x128 tile, software-pipelined staging:
//   buffer_load -> VGPR (issued 1 iter ahead, stays in flight across barriers)
//   -> ds_write -> MFMA. No global_load_lds (its LDS-write semantics force a
//   vmcnt(0) drain at s_barrier, exposing full load latency at ~1.5 blocks/CU).
// Workspace: 64KB + 4.72MB (Wb) + Mpad*3072*2 (~49.5MB) ~= 55 MB.

typedef __attribute__((ext_vector_type(8))) short bf16x8;
typedef __attribute__((ext_vector_type(4))) float f32x4;

#define K_DIM 3072
#define N_DIM 768

__device__ __forceinline__ unsigned short f2bf(float f) {
  unsigned int u = __float_as_uint(f);
  u += 0x7fffu + ((u >> 16) & 1u);   // RNE
  return (unsigned short)(u >> 16);
}

// ---------------- prep: wconv + layout, one launch ----------------
__global__ __launch_bounds__(1024)
void prep_kernel(const float* __restrict__ W, unsigned short* __restrict__ Wb, int w4,
                 const float* __restrict__ iw, int P,
                 int* __restrict__ tokBase, int* __restrict__ tokMask, int NB_W) {
  int bid = blockIdx.x;
  int tid = threadIdx.x;
  if (bid < NB_W) {
    int idx = bid * 1024 + tid;
    if (idx < w4) {
      float4 f = *(const float4*)(W + (size_t)idx * 4);
      ushort4 o;
      o.x = f2bf(f.x); o.y = f2bf(f.y); o.z = f2bf(f.z); o.w = f2bf(f.w);
      *(ushort4*)(Wb + (size_t)idx * 4) = o;
    }
    return;
  }
  // ---- layout (single block) ----
  __shared__ double s_wsum[16];
  __shared__ double s_avg;
  __shared__ int s_cnt[1024];
  float v = (tid < P) ? iw[tid] : 0.0f;
  double d = (double)v;
#pragma unroll
  for (int off = 32; off > 0; off >>= 1) d += __shfl_down(d, off, 64);
  if ((tid & 63) == 0) s_wsum[tid >> 6] = d;
  __syncthreads();
  if (tid == 0) {
    double s = 0.0;
    for (int i = 0; i < 16; ++i) s += s_wsum[i];
    s_avg = s / (double)P;
  }
  __syncthreads();
  int cnt = 0, sz = 32;
  if (tid < P) {
    double val = 32.0 * pow(s_avg / (double)v, 0.05);
    if (val > 32.0) val = 32.0;
    // nearest of {32,16,8,4}; ties (24,12,6) -> larger (np.argmin first index)
    sz = (val >= 24.0) ? 32 : (val >= 12.0) ? 16 : (val >= 6.0) ? 8 : 4;
    cnt = (sz < 32) ? (32 / sz) : 1;
  }
  s_cnt[tid] = cnt;
  __syncthreads();
  for (int dl = 1; dl < 1024; dl <<= 1) {  // Hillis-Steele inclusive scan
    int add = (tid >= dl) ? s_cnt[tid - dl] : 0;
    __syncthreads();
    s_cnt[tid] += add;
    __syncthreads();
  }
  if (tid < P) {
    int off = s_cnt[tid] - cnt;                 // exclusive offset
    int ini_col = (tid * 32) & 1023;            // (i*ps) % H
    int ini_row = (tid * 32 * 32) >> 10;        // (i*ps*ps) / H
    if (sz == 32) {
      tokBase[off] = ini_row * 1024 + ini_col;
      tokMask[off] = 31;
    } else {
      int ns = 32 / sz;
      for (int j = 0; j < ns; ++j) {
        int r = ini_row + (j * sz) / ns;
        int c = ini_col + ((j * sz) & 31);
        tokBase[off + j] = r * 1024 + c;
        tokMask[off + j] = sz - 1;
      }
    }
  }
}

// ---------------- gather: one block per A row ----------------
// A[c,f] = patch[c, (f>>log2s)&(s-1), f&(s-1)]  (flat-index periodicity)
__global__ __launch_bounds__(256)
void gather_kernel(const float* __restrict__ x,
                   const int* __restrict__ tokBase,
                   const int* __restrict__ tokMask,
                   unsigned short* __restrict__ Ab) {
  int t = blockIdx.x;            // token
  int b = blockIdx.y;            // batch
  int T = gridDim.x;
  int m = b * T + t;
  int base = tokBase[t];         // block-uniform -> scalar loads
  int mask = tokMask[t];
  int sh = __popc(mask);
  const float* xb = x + (size_t)b * 3145728 + (size_t)base;
  unsigned short* arow = Ab + (size_t)m * K_DIM;
#pragma unroll
  for (int it = 0; it < 3; ++it) {
    int g = it * 256 + threadIdx.x;   // float4-group 0..767
    int p = g * 4;
    int c = p >> 10;
    int f = p & 1023;
    int h = (f >> sh) & mask;
    int w = f & mask;
    float4 fv = *(const float4*)(xb + (size_t)c * 1048576 + h * 1024 + w);
    ushort4 o;
    o.x = f2bf(fv.x); o.y = f2bf(fv.y); o.z = f2bf(fv.z); o.w = f2bf(fv.w);
    *(ushort4*)(arow + p) = o;
  }
}

// ---------------- gemm: pipelined reg-staged 128x128x32 ----------------
__global__ __launch_bounds__(256, 2)
void gemm_kernel(const unsigned short* __restrict__ A, const unsigned short* __restrict__ Wb,
                 const float* __restrict__ bias, float* __restrict__ out, int Mtot) {
  __shared__ unsigned short Alds[128 * 32];  // 8 KB, rows of 64B (conflict-clean)
  __shared__ unsigned short Blds[128 * 32];  // 8 KB
  int tid = threadIdx.x;
  int lane = tid & 63;
  int wave = tid >> 6;
  int wr = wave >> 1, wc = wave & 1;
  int mBase = blockIdx.y * 128;
  int nBase = blockIdx.x * 128;

  f32x4 acc[4][4] = {};

  // staging map: chunk id = tid (+256): row = id>>2, 16B-chunk = id&3
  const unsigned short* Ag0 = A + (size_t)(mBase + (tid >> 2)) * K_DIM + (tid & 3) * 8;
  const unsigned short* Ag1 = Ag0 + (size_t)64 * K_DIM;
  const unsigned short* Bg0 = Wb + (size_t)(nBase + (tid >> 2)) * K_DIM + (tid & 3) * 8;
  const unsigned short* Bg1 = Bg0 + (size_t)64 * K_DIM;
  unsigned short* Al0 = Alds + tid * 8;       // == (row*32 + chunk*8)
  unsigned short* Al1 = Al0 + 2048;
  unsigned short* Bl0 = Blds + tid * 8;
  unsigned short* Bl1 = Bl0 + 2048;

  int rr = lane & 15, q = lane >> 4;

  int4 ra0, ra1, rb0, rb1;       // set X (even iters)
  int4 sa0, sa1, sb0, sb1;       // set Y (odd iters)

  // prologue: load k=0 into set X
  ra0 = *(const int4*)(Ag0); ra1 = *(const int4*)(Ag1);
  rb0 = *(const int4*)(Bg0); rb1 = *(const int4*)(Bg1);

#define MFMA_STAGE()                                                        \
  {                                                                         \
    bf16x8 aF[4], bF[4];                                                    \
    _Pragma("unroll")                                                       \
    for (int i = 0; i < 4; ++i)                                             \
      aF[i] = *(const bf16x8*)&Alds[(wr * 64 + i * 16 + rr) * 32 + q * 8];  \
    _Pragma("unroll")                                                       \
    for (int j = 0; j < 4; ++j)                                             \
      bF[j] = *(const bf16x8*)&Blds[(wc * 64 + j * 16 + rr) * 32 + q * 8];  \
    _Pragma("unroll")                                                       \
    for (int i = 0; i < 4; ++i)                                             \
      _Pragma("unroll")                                                     \
      for (int j = 0; j < 4; ++j)                                           \
        acc[i][j] = __builtin_amdgcn_mfma_f32_16x16x32_bf16(aF[i], bF[j],   \
                                                            acc[i][j], 0, 0, 0); \
  }

  for (int k0 = 0; k0 < K_DIM; k0 += 64) {
    // ---- even half: consume set X (tile k0), prefetch tile k0+32 into Y ----
    if (k0 + 32 < K_DIM) {
      sa0 = *(const int4*)(Ag0 + k0 + 32); sa1 = *(const int4*)(Ag1 + k0 + 32);
      sb0 = *(const int4*)(Bg0 + k0 + 32); sb1 = *(const int4*)(Bg1 + k0 + 32);
    }
    __syncthreads();                       // prev readers done; loads stay in flight
    *(int4*)Al0 = ra0; *(int4*)Al1 = ra1;  // waits only on set-X vmcnt (arrived)
    *(int4*)Bl0 = rb0; *(int4*)Bl1 = rb1;
    __syncthreads();                       // tile visible (lgkmcnt drain only)
    MFMA_STAGE();

    // ---- odd half: consume set Y (tile k0+32), prefetch k0+64 into X ----
    if (k0 + 64 < K_DIM) {
      ra0 = *(const int4*)(Ag0 + k0 + 64); ra1 = *(const int4*)(Ag1 + k0 + 64);
      rb0 = *(const int4*)(Bg0 + k0 + 64); rb1 = *(const int4*)(Bg1 + k0 + 64);
    }
    __syncthreads();
    *(int4*)Al0 = sa0; *(int4*)Al1 = sa1;
    *(int4*)Bl0 = sb0; *(int4*)Bl1 = sb1;
    __syncthreads();
    MFMA_STAGE();
  }

  // epilogue: C/D layout col=lane&15, row=(lane>>4)*4+reg
#pragma unroll
  for (int j = 0; j < 4; ++j) {
    int n = nBase + wc * 64 + j * 16 + rr;
    float bv = bias[n];
#pragma unroll
    for (int i = 0; i < 4; ++i) {
      int mrow = mBase + wr * 64 + i * 16 + q * 4;
#pragma unroll
      for (int r2 = 0; r2 < 4; ++r2) {
        int m = mrow + r2;
        if (m < Mtot) out[(size_t)m * N_DIM + n] = acc[i][j][r2] + bv;
      }
    }
  }
}

extern "C" void kernel_launch(void* const* d_in, const int* in_sizes, int n_in,
                              void* d_out, int out_size, void* d_ws, size_t ws_size,
                              hipStream_t stream) {
  const float* x  = (const float*)d_in[0];
  const float* iw = (const float*)d_in[1];
  const float* W  = (const float*)d_in[2];
  const float* b  = (const float*)d_in[3];
  int P = in_sizes[1];                        // 992
  int B = in_sizes[0] / (3 * 1024 * 1024);    // 8
  int E = in_sizes[3];                        // 768
  int T = out_size / (B * E);                 // 995
  int Mtot = B * T;                           // 7960
  int Mpad = (Mtot + 127) & ~127;             // 8064

  char* ws = (char*)d_ws;
  int* tokBase = (int*)ws;                              // 32 KB
  int* tokMask = (int*)(ws + 32768);                    // 32 KB
  unsigned short* Wb = (unsigned short*)(ws + 65536);   // 4.72 MB
  unsigned short* Ab = (unsigned short*)(ws + 65536 + (size_t)E * K_DIM * 2);

  int w4 = E * K_DIM / 4;                     // 589824
  int NB_W = (w4 + 1023) / 1024;              // 576
  prep_kernel<<<NB_W + 1, 1024, 0, stream>>>(W, Wb, w4, iw, P, tokBase, tokMask, NB_W);

  dim3 gGrid(T, B);
  gather_kernel<<<gGrid, 256, 0, stream>>>(x, tokBase, tokMask, Ab);

  dim3 grid(N_DIM / 128, Mpad / 128);
  gemm_kernel<<<grid, 256, 0, stream>>>(Ab, Wb, b, (float*)d_out, Mtot);
}

// Round 5
// 248.963 us; speedup vs baseline: 1.0562x; 1.0533x over previous
//
#include <hip/hip_runtime.h>

// PatchEmbedding2 on MI355X — round 5: LDS-free fragment-direct GEMM.
// __syncthreads() forces s_waitcnt vmcnt(0) (r4 evidence: reg-pipeline regressed;
// replay FETCH~0 at identical dur => latency/LDS-bound, not BW). So: pre-arrange
// BOTH operands in MFMA fragment order in global memory; GEMM is single-wave
// blocks loading fragments straight to VGPRs. No LDS, no barriers, no drains.
//
// Fragment order (16x16x32 bf16, verified by r2 passing): lane l holds
// X[row = l&15][k = (l>>4)*8 + j], j=0..7. A 16-row x 32-k panel = 64 lanes x
// 16 B = 1 KB block. Af[((mt*96 + g)*64 + l)*8 shorts], mt = m>>4, g = k>>5.
// Bf likewise with nt = n>>4.
// Workspace: 64KB + 4.72MB (Bf) + 500*96*1KB (~49.2MB) ~= 54 MB.

typedef __attribute__((ext_vector_type(8))) short bf16x8;
typedef __attribute__((ext_vector_type(8))) unsigned short u16x8;
typedef __attribute__((ext_vector_type(4))) float f32x4;

#define K_DIM 3072
#define N_DIM 768

__device__ __forceinline__ unsigned short f2bf(float f) {
  unsigned int u = __float_as_uint(f);
  u += 0x7fffu + ((u >> 16) & 1u);   // RNE
  return (unsigned short)(u >> 16);
}

// ---------------- prep: W -> bf16 fragment order + token layout ----------------
// chunk c: l = c&63; u = c>>6; g = u%96; nt = u/96.
// value: B[n = nt*16 + (l&15)][k = g*32 + (l>>4)*8 + j], src W[n*3072 + k].
__global__ __launch_bounds__(1024)
void prep_kernel(const float* __restrict__ W, unsigned short* __restrict__ Bf,
                 const float* __restrict__ iw, int P,
                 int* __restrict__ tokBase, int* __restrict__ tokMask, int NB_W) {
  int bid = blockIdx.x;
  int tid = threadIdx.x;
  if (bid < NB_W) {
    // 1024 threads x 2 chunks less often; here: 2048 chunks/block? Use 1024 thr x
    // 2 chunks per thread? NB_W covers 48*96*64 = 294912 chunks; 2048/block.
#pragma unroll
    for (int s = 0; s < 2; ++s) {
      int c = bid * 2048 + tid + s * 1024;
      if (c < 48 * 96 * 64) {
        int l = c & 63;
        int u = c >> 6;
        int g = u % 96;
        int nt = u / 96;
        int n = nt * 16 + (l & 15);
        int k = g * 32 + (l >> 4) * 8;
        const float* src = W + (size_t)n * K_DIM + k;
        float4 f0 = *(const float4*)src;
        float4 f1 = *(const float4*)(src + 4);
        u16x8 o;
        o[0] = f2bf(f0.x); o[1] = f2bf(f0.y); o[2] = f2bf(f0.z); o[3] = f2bf(f0.w);
        o[4] = f2bf(f1.x); o[5] = f2bf(f1.y); o[6] = f2bf(f1.z); o[7] = f2bf(f1.w);
        *(u16x8*)(Bf + (size_t)c * 8) = o;
      }
    }
    return;
  }
  // ---- layout (single block, proven r2 code) ----
  __shared__ double s_wsum[16];
  __shared__ double s_avg;
  __shared__ int s_cnt[1024];
  float v = (tid < P) ? iw[tid] : 0.0f;
  double d = (double)v;
#pragma unroll
  for (int off = 32; off > 0; off >>= 1) d += __shfl_down(d, off, 64);
  if ((tid & 63) == 0) s_wsum[tid >> 6] = d;
  __syncthreads();
  if (tid == 0) {
    double s = 0.0;
    for (int i = 0; i < 16; ++i) s += s_wsum[i];
    s_avg = s / (double)P;
  }
  __syncthreads();
  int cnt = 0, sz = 32;
  if (tid < P) {
    double val = 32.0 * pow(s_avg / (double)v, 0.05);
    if (val > 32.0) val = 32.0;
    sz = (val >= 24.0) ? 32 : (val >= 12.0) ? 16 : (val >= 6.0) ? 8 : 4;
    cnt = (sz < 32) ? (32 / sz) : 1;
  }
  s_cnt[tid] = cnt;
  __syncthreads();
  for (int dl = 1; dl < 1024; dl <<= 1) {
    int add = (tid >= dl) ? s_cnt[tid - dl] : 0;
    __syncthreads();
    s_cnt[tid] += add;
    __syncthreads();
  }
  if (tid < P) {
    int off = s_cnt[tid] - cnt;
    int ini_col = (tid * 32) & 1023;
    int ini_row = (tid * 32 * 32) >> 10;
    if (sz == 32) {
      tokBase[off] = ini_row * 1024 + ini_col;
      tokMask[off] = 31;
    } else {
      int ns = 32 / sz;
      for (int j = 0; j < ns; ++j) {
        int r = ini_row + (j * sz) / ns;
        int c = ini_col + ((j * sz) & 31);
        tokBase[off + j] = r * 1024 + c;
        tokMask[off + j] = sz - 1;
      }
    }
  }
}

// ---------------- gather: x -> bf16 A in fragment order ----------------
// block = one mt (16 A-rows). thread: fixed l (= tid&63) -> fixed m/token;
// loops g = (tid>>6) + 4*i. A[m][k] = x[b, k>>10, base + ((f>>sh)&mask)*1024
// + (f&mask)], f = k&1023 (flat-index periodicity, verified r2).
__global__ __launch_bounds__(256)
void gather_kernel(const float* __restrict__ x,
                   const int* __restrict__ tokBase,
                   const int* __restrict__ tokMask,
                   unsigned short* __restrict__ Af, int T, int Mtot) {
  int mt = blockIdx.x;
  int tid = threadIdx.x;
  int l = tid & 63;
  int g0 = tid >> 6;
  int m = mt * 16 + (l & 15);
  int q = l >> 4;
  bool valid = (m < Mtot);
  int b = 0, base = 0, mask = 31, sh = 5;
  if (valid) {
    b = m / T;
    int t = m - b * T;
    base = tokBase[t];
    mask = tokMask[t];
    sh = __popc(mask);
  }
  const float* xb = x + (size_t)b * 3145728 + base;
  unsigned short* outp = Af + ((size_t)mt * 96 + g0) * 512 + l * 8;
#pragma unroll
  for (int i = 0; i < 24; ++i) {
    int g = g0 + i * 4;
    int k = g * 32 + q * 8;
    u16x8 o = {0, 0, 0, 0, 0, 0, 0, 0};
    if (valid) {
      int c = k >> 10;
      int f = k & 1023;
      if (sh >= 3) {                       // s in {8,16,32}: 8 contiguous floats
        int h = (f >> sh) & mask;
        int w = f & mask;
        const float* s = xb + (size_t)c * 1048576 + h * 1024 + w;
        float4 f0 = *(const float4*)s;
        float4 f1 = *(const float4*)(s + 4);
        o[0] = f2bf(f0.x); o[1] = f2bf(f0.y); o[2] = f2bf(f0.z); o[3] = f2bf(f0.w);
        o[4] = f2bf(f1.x); o[5] = f2bf(f1.y); o[6] = f2bf(f1.z); o[7] = f2bf(f1.w);
      } else {                             // s == 4 generic (unused by this input)
#pragma unroll
        for (int j = 0; j < 8; ++j) {
          int ff = f + j;
          int h = (ff >> sh) & mask;
          int w = ff & mask;
          o[j] = f2bf(xb[(size_t)c * 1048576 + h * 1024 + w]);
        }
      }
    }
    *(u16x8*)(outp + (size_t)i * 2048) = o;   // g advances by 4 => 4*512 shorts
  }
}

// ---------------- gemm: LDS-free, 1 wave = 64x64 tile, fragments from global ----
__global__ __launch_bounds__(64)
void gemm_kernel(const short* __restrict__ Af, const short* __restrict__ Bf,
                 const float* __restrict__ bias, float* __restrict__ out, int Mtot) {
  int l = threadIdx.x;
  int wn = blockIdx.x;     // 0..11   (n-stripe, fastest: A-slice readers adjacent)
  int wm = blockIdx.y;     // 0..124
  int loff = l * 8;        // shorts

  const short* pA[4];
  const short* pB[4];
#pragma unroll
  for (int i = 0; i < 4; ++i) pA[i] = Af + ((size_t)(wm * 4 + i) * 96) * 512 + loff;
#pragma unroll
  for (int j = 0; j < 4; ++j) pB[j] = Bf + ((size_t)(wn * 4 + j) * 96) * 512 + loff;

  f32x4 acc[4][4] = {};
  bf16x8 a0[4], b0[4], a1[4], b1[4];

#define LOADSET(A_, B_, G_)                                   \
  {                                                           \
    _Pragma("unroll")                                         \
    for (int i = 0; i < 4; ++i)                               \
      A_[i] = *(const bf16x8*)(pA[i] + (size_t)(G_) * 512);   \
    _Pragma("unroll")                                         \
    for (int j = 0; j < 4; ++j)                               \
      B_[j] = *(const bf16x8*)(pB[j] + (size_t)(G_) * 512);   \
  }
#define MFMASET(A_, B_)                                                      \
  {                                                                          \
    _Pragma("unroll")                                                        \
    for (int i = 0; i < 4; ++i)                                              \
      _Pragma("unroll")                                                      \
      for (int j = 0; j < 4; ++j)                                            \
        acc[i][j] = __builtin_amdgcn_mfma_f32_16x16x32_bf16(A_[i], B_[j],    \
                                                            acc[i][j], 0, 0, 0); \
  }

  LOADSET(a0, b0, 0);
  for (int g = 0; g < 94; g += 2) {
    LOADSET(a1, b1, g + 1);
    MFMASET(a0, b0);
    LOADSET(a0, b0, g + 2);
    MFMASET(a1, b1);
  }
  LOADSET(a1, b1, 95);
  MFMASET(a0, b0);   // g = 94
  MFMASET(a1, b1);   // g = 95

  // epilogue: C/D layout col=lane&15, row=(lane>>4)*4+reg (r2-verified)
  int rr = l & 15, q = l >> 4;
#pragma unroll
  for (int j = 0; j < 4; ++j) {
    int n = wn * 64 + j * 16 + rr;
    float bv = bias[n];
#pragma unroll
    for (int i = 0; i < 4; ++i) {
      int mrow = wm * 64 + i * 16 + q * 4;
#pragma unroll
      for (int r2 = 0; r2 < 4; ++r2) {
        int m = mrow + r2;
        if (m < Mtot) out[(size_t)m * N_DIM + n] = acc[i][j][r2] + bv;
      }
    }
  }
#undef LOADSET
#undef MFMASET
}

extern "C" void kernel_launch(void* const* d_in, const int* in_sizes, int n_in,
                              void* d_out, int out_size, void* d_ws, size_t ws_size,
                              hipStream_t stream) {
  const float* x  = (const float*)d_in[0];
  const float* iw = (const float*)d_in[1];
  const float* W  = (const float*)d_in[2];
  const float* b  = (const float*)d_in[3];
  int P = in_sizes[1];                        // 992
  int B = in_sizes[0] / (3 * 1024 * 1024);    // 8
  int E = in_sizes[3];                        // 768
  int T = out_size / (B * E);                 // 995
  int Mtot = B * T;                           // 7960
  int Mpad = (Mtot + 63) & ~63;               // 8000
  int mtBlocks = Mpad / 16;                   // 500

  char* ws = (char*)d_ws;
  int* tokBase = (int*)ws;                              // 32 KB
  int* tokMask = (int*)(ws + 32768);                    // 32 KB
  unsigned short* Bf = (unsigned short*)(ws + 65536);   // 4.72 MB (frag order)
  unsigned short* Af = (unsigned short*)(ws + 65536 + (size_t)E * K_DIM * 2);

  int NB_W = (48 * 96 * 64 + 2047) / 2048;    // 144 blocks x 2048 chunks
  prep_kernel<<<NB_W + 1, 1024, 0, stream>>>(W, Bf, iw, P, tokBase, tokMask, NB_W);

  gather_kernel<<<mtBlocks, 256, 0, stream>>>(x, tokBase, tokMask, Af, T, Mtot);

  dim3 grid(N_DIM / 64, Mpad / 64);           // (12, 125) single-wave blocks
  gemm_kernel<<<grid, 64, 0, stream>>>((const short*)Af, (const short*)Bf, b,
                                       (float*)d_out, Mtot);
}